// Round 13
// baseline (115.043 us; speedup 1.0000x reference)
//
#include <hip/hip_runtime.h>
#include <hip/hip_fp16.h>
#include <math.h>

#define PATCH 41
#define PP 1681          // 41*41
#define NB 8
#define STRIDE 10
#define NTH 192          // 3 waves
#define HR 5             // s_H ox-slot stride (4 used + 1 pad)
#define PPB 4            // patches per block (persistent, prefetch-pipelined)
#define TAIL (PP - 8 * NTH)   // 145

__device__ __forceinline__ constexpr float tri16(int k) {
    float d = (float)k + 0.5f - 8.0f;
    float a = d < 0.0f ? -d : d;
    return (8.0f - a) * 0.125f;   // == pk[i][j] factor bit-exactly; all values n*2^-4 (exact in f16)
}

// per-pixel core: grad + folded weight -> packed 8-bin f16 contrib (16B)
// (octant-direct binning + 64-bit-shift pack: validated; R7 scalar form)
__device__ __forceinline__ uint4 pixel_contrib(float gx, float gy, float w) {
    float X = gx + 1e-10f;
    float mag = __builtin_amdgcn_sqrtf(fmaf(gx, gx, fmaf(gy, gy, 1e-10f))) * w;

    float ax = fabsf(X), ay = fabsf(gy);
    float mx = fmaxf(ax, ay), mn = fminf(ax, ay);
    float r = mn * __builtin_amdgcn_rcpf(fmaxf(mx, 1e-30f));
    float r2 = r * r;
    float a4 = fmaf(r2, -0.0149238f, 0.0670406f);
    a4 = fmaf(r2, a4, -0.1482457f);
    a4 = fmaf(r2, a4, 0.2464287f);
    a4 = fmaf(r2, a4, -0.4235106f);
    a4 = fmaf(r2, a4, 1.2732106f);
    a4 *= r;

    bool sw = ay > ax;
    bool xn = X < 0.0f;
    bool yn = gy < 0.0f;
    int q = (xn ? 2 : 0) + ((sw != xn) ? 1 : 0);
    int b0 = yn ? 7 - q : q;              // bin for (1-w1) mass
    bool f = (sw != xn) != yn;
    float ma = a4 * mag;
    float mb = mag - ma;
    float v0 = f ? ma : mb;               // mass for bin b0
    float v1 = f ? mb : ma;               // mass for bin (b0+1)&7

    unsigned combo = __builtin_bit_cast(unsigned, __builtin_amdgcn_cvt_pkrtz(v0, v1));
    int sh = (b0 & 3) << 4;
    unsigned long long A = (unsigned long long)combo << sh;
    unsigned long long B = ((b0 & 3) == 3) ? (unsigned long long)(combo >> 16) : 0ull;
    bool lohalf = b0 < 4;
    unsigned long long lo = lohalf ? A : B;
    unsigned long long hi = lohalf ? B : A;
    uint4 cw;
    cw.x = (unsigned)lo; cw.y = (unsigned)(lo >> 32);
    cw.z = (unsigned)hi; cw.w = (unsigned)(hi >> 32);
    return cw;
}

__device__ __forceinline__ __half2 u2h2(unsigned v) {
    return __builtin_bit_cast(__half2, v);
}

// lane i <- lane i-1 within its 16-lane DPP row; row-start lanes -> 0
__device__ __forceinline__ unsigned dpp_prev(unsigned v) {
    return (unsigned)__builtin_amdgcn_update_dpp(0, (int)v, 0x111, 0xF, 0xF, true); // row_shr:1
}
// lane i <- lane i+1 within its 16-lane DPP row; row-end lanes -> 0
__device__ __forceinline__ unsigned dpp_next(unsigned v) {
    return (unsigned)__builtin_amdgcn_update_dpp(0, (int)v, 0x101, 0xF, 0xF, true); // row_shl:1
}

// R13: R12 + ONE added line — sched_barrier(0) between the m/u/d LDS
// preloads and the compute loop. R5/R6 showed the scheduler re-SINKS
// preloads next to uses (VGPR pinned 32/40 -> ~11 lgkm stall points/patch);
// R6's fence covered only the global staging loads. sched_barrier(0) is a
// compile-time wall: all ~35 ds_read_b32 (merge to ds_read2) must issue as
// one clause before any compute -> one lgkm wait, live ranges forced
// (budget 85 VGPR @ (192,6)). Diagnostic: VGPR must jump to ~70-85.
__global__ __launch_bounds__(NTH, 6) void sift_desc_kernel(
        const float* __restrict__ x,   // [N,1,41,41]
        const float* __restrict__ gk,  // unused: recomputed via exp2
        const float* __restrict__ pk,  // unused: recomputed exactly
        float* __restrict__ out,       // [N,128]
        int n)
{
    const int t = threadIdx.x;
    const int base = blockIdx.x * PPB;

    __shared__ __align__(16) float sA[PP];               // 6.7 KB raw patch buf A
    __shared__ __align__(16) float sB[PP];               // 6.7 KB raw patch buf B
    __shared__ __align__(16) __half s_H[49 * HR * NB];   // 3.9 KB, rows 0-3,45-48 zero

    // ---- one-time: zero H pad rows 0-3,45-48 ----
    if (t < 160) {
        int dw = (t < 80) ? t : (820 + t);
        ((unsigned*)s_H)[dw] = 0u;
    }

    // ---- per-thread P1 constants (valid for t<164; harmless garbage else) ----
    const int row = t >> 2;
    const int ox  = t & 3;
    const int cb  = ox * STRIDE;
    const bool ox0 = (ox == 0);
    const bool ox3 = (ox == 3);
    const float drow = (float)(row - 20);
    const float rf = __builtin_amdgcn_exp2f(drow * drow * -8.582362e-4f);
    const __half2 z2 = __float2half2_rn(0.0f);
    const __half2 wl[4] = {
        ox0 ? z2 : __float2half2_rn(tri16(0)),
        ox0 ? z2 : __float2half2_rn(tri16(1)),
        ox0 ? z2 : __float2half2_rn(tri16(2)),
        ox0 ? z2 : __float2half2_rn(tri16(3))
    };
    const int rb = row * PATCH + cb;                                      // M row base (col cb)
    const int ru = (row > 0 ? row - 1 : 0) * PATCH + cb;                  // up row
    const int rd = (row < PATCH - 1 ? row + 1 : PATCH - 1) * PATCH + cb;  // down row

    // w[] is PATCH-INVARIANT: hoisted (R11/R12); same exp2 expression -> bit-exact.
    float w[11];
    #pragma unroll
    for (int i = 0; i < 11; ++i) {
        float dc = (float)(cb + i - 20);
        w[i] = __builtin_amdgcn_exp2f(dc * dc * -8.582362e-4f) * rf;
    }

    // ---- stage patch base+0 into sA (batched: all loads, then all writes) ----
    {
        const float* gp = x + (size_t)base * PP;
        float stg[9];
        #pragma unroll
        for (int it = 0; it < 8; ++it) stg[it] = gp[it * NTH + t];
        stg[8] = (t < TAIL) ? gp[8 * NTH + t] : 0.0f;
        #pragma unroll
        for (int it = 0; it < 8; ++it) sA[it * NTH + t] = stg[it];
        if (t < TAIL) sA[8 * NTH + t] = stg[8];
    }
    __syncthreads();

    #pragma unroll
    for (int pi = 0; pi < PPB; ++pi) {
        if (base + pi >= n) break;                       // uniform guard
        const float* sC = (pi & 1) ? sB : sA;            // folds to concrete array
        float*       sN = (pi & 1) ? sA : sB;
        const bool hn = (pi + 1 < PPB) && (base + pi + 1 < n);

        // -- issue next-patch staging loads EARLY (drain hides under P1) --
        float stg[9];
        if (hn) {
            const float* gp = x + (size_t)(base + pi + 1) * PP;
            #pragma unroll
            for (int it = 0; it < 8; ++it) stg[it] = gp[it * NTH + t];
            stg[8] = (t < TAIL) ? gp[8 * NTH + t] : 0.0f;
        }
        __builtin_amdgcn_sched_barrier(0);   // pin: global loads stay above P1

        // ---- P1+P2 fused, owned-pixel scheme (validated R2/R7) ----
        if (t < PATCH * 4) {
            float m[13], u[11], d[11];
            // m: cols cb-1 .. cb+11, ends index-clamped == replicate pad
            m[0]  = sC[rb + (ox0 ? 0 : -1)];
            #pragma unroll
            for (int i = 1; i < 12; ++i) m[i] = sC[rb + i - 1];
            m[12] = sC[rb + (ox3 ? 10 : 11)];
            #pragma unroll
            for (int i = 0; i < 11; ++i) u[i] = sC[ru + i];
            #pragma unroll
            for (int i = 0; i < 11; ++i) d[i] = sC[rd + i];

            // R13: compile-time wall — the 35 ds_reads above may NOT sink
            // below this point. Forces one up-front LDS clause + one lgkm
            // wait; compute below runs stall-free. (The R5/R6 sink fix,
            // now applied to the LDS preloads, not just global staging.)
            __builtin_amdgcn_sched_barrier(0);

            __half2 a0 = z2, a1 = z2, a2 = z2, a3 = z2;

            #pragma unroll
            for (int k = 0; k <= 10; ++k) {
                uint4 cw = pixel_contrib(m[k + 2] - m[k], d[k] - u[k], w[k]);

                // own window slot kx = k+4, exact-f16 tri constant
                const __half2 wo = __float2half2_rn(tri16(k + 4));
                a0 = __hfma2(u2h2(cw.x), wo, a0);
                a1 = __hfma2(u2h2(cw.y), wo, a1);
                a2 = __hfma2(u2h2(cw.z), wo, a2);
                a3 = __hfma2(u2h2(cw.w), wo, a3);

                if (k == 1) {
                    // my kx=15 (col cb+11) = right lane's k=1 eval; tri16(15)
                    unsigned rx = dpp_next(cw.x);
                    unsigned ry = dpp_next(cw.y);
                    unsigned rz = dpp_next(cw.z);
                    unsigned rw = dpp_next(cw.w);
                    rx = ox3 ? 0u : rx;  ry = ox3 ? 0u : ry;   // ox3: OOB + junk-src
                    rz = ox3 ? 0u : rz;  rw = ox3 ? 0u : rw;
                    const __half2 wr = __float2half2_rn(tri16(15));
                    a0 = __hfma2(u2h2(rx), wr, a0);
                    a1 = __hfma2(u2h2(ry), wr, a1);
                    a2 = __hfma2(u2h2(rz), wr, a2);
                    a3 = __hfma2(u2h2(rw), wr, a3);
                }
                if (k >= 6 && k < 10) {
                    // kx = k-6 = left lane's k=6..9 ONLY (k=10 dup was R1 bug);
                    // ox0 weight zero kills prev-row data; row-start DPP-zero
                    const __half2 wk = wl[k - 6];
                    a0 = __hfma2(u2h2(dpp_prev(cw.x)), wk, a0);
                    a1 = __hfma2(u2h2(dpp_prev(cw.y)), wk, a1);
                    a2 = __hfma2(u2h2(dpp_prev(cw.z)), wk, a2);
                    a3 = __hfma2(u2h2(dpp_prev(cw.w)), wk, a3);
                }
            }

            uint4 hv;
            hv.x = __builtin_bit_cast(unsigned, a0);
            hv.y = __builtin_bit_cast(unsigned, a1);
            hv.z = __builtin_bit_cast(unsigned, a2);
            hv.w = __builtin_bit_cast(unsigned, a3);
            *(uint4*)&s_H[((row + 4) * HR + ox) * NB] = hv;   // phys row = row+4
        }
        __syncthreads();   // barA: s_H complete; all sC reads done

        // -- write staged data (loads in flight since pre-P1; vmcnt waits here) --
        if (hn) {
            #pragma unroll
            for (int it = 0; it < 8; ++it) sN[it * NTH + t] = stg[it];
            if (t < TAIL) sN[8 * NTH + t] = stg[8];
        }

        // ---- P4': merged pool+normalize (t<64). Same fmaf ky order as the
        // old P3 -> bit-identical. Reads s_H; fenced from next P1's rewrite
        // by the trailing barrier.
        if (t < 64) {
            const int b   = t >> 4;
            const int oy  = (t >> 2) & 3;
            const int oxx = t & 3;
            const __half* hp = &s_H[(oy * STRIDE * HR + oxx) * NB + b]; // phys row oy*10
            float a = 0.0f, bb = 0.0f;
            #pragma unroll
            for (int ky = 0; ky < 16; ++ky) {
                a  = fmaf(tri16(ky), __half2float(hp[ky * HR * NB]),     a);
                bb = fmaf(tri16(ky), __half2float(hp[ky * HR * NB + 4]), bb);
            }

            float ss = fmaf(a, a, bb * bb);
            #pragma unroll
            for (int o = 32; o > 0; o >>= 1) ss += __shfl_xor(ss, o);
            float inv = 1.0f / fmaxf(__builtin_amdgcn_sqrtf(ss), 1e-12f);
            a  = fminf(fmaxf(a * inv, 0.0f), 0.2f);
            bb = fminf(fmaxf(bb * inv, 0.0f), 0.2f);

            float ss2 = fmaf(a, a, bb * bb);
            #pragma unroll
            for (int o = 32; o > 0; o >>= 1) ss2 += __shfl_xor(ss2, o);
            float inv2 = 1.0f / fmaxf(__builtin_amdgcn_sqrtf(ss2), 1e-12f);
            a *= inv2; bb *= inv2;

            float l1 = a + bb;                     // both >= 0 after clip
            #pragma unroll
            for (int o = 32; o > 0; o >>= 1) l1 += __shfl_xor(l1, o);
            float invl = 1.0f / fmaxf(l1, 1e-12f);

            float* op = out + (size_t)(base + pi) * 128;
            op[t]      = __builtin_amdgcn_sqrtf(fmaf(a,  invl, 1e-10f));
            op[t + 64] = __builtin_amdgcn_sqrtf(fmaf(bb, invl, 1e-10f));
        }
        __syncthreads();   // barB: P4' s_H reads + sN writes complete before
                           // next iteration's P1 (rewrites s_H, reads sN)
    }
}

extern "C" void kernel_launch(void* const* d_in, const int* in_sizes, int n_in,
                              void* d_out, int out_size, void* d_ws, size_t ws_size,
                              hipStream_t stream) {
    const float* x  = (const float*)d_in[0];
    const float* gk = (const float*)d_in[1];
    const float* pk = (const float*)d_in[2];
    float* out = (float*)d_out;
    const int n = in_sizes[0] / PP;   // 8192 patches
    const int grid = (n + PPB - 1) / PPB;
    sift_desc_kernel<<<grid, NTH, 0, stream>>>(x, gk, pk, out, n);
}

// Round 14
// 111.327 us; speedup vs baseline: 1.0334x; 1.0334x over previous
//
#include <hip/hip_runtime.h>
#include <hip/hip_fp16.h>
#include <math.h>

#define PATCH 41
#define PP 1681          // 41*41
#define NB 8
#define STRIDE 10
#define NTH 192          // 3 waves, each wave = one INDEPENDENT patch (no barriers)
#define HR 5             // s_H ox-slot stride (4 used + 1 pad)

__device__ __forceinline__ constexpr float tri16(int k) {
    float d = (float)k + 0.5f - 8.0f;
    float a = d < 0.0f ? -d : d;
    return (8.0f - a) * 0.125f;   // == pk[i][j] factor bit-exactly; all values n*2^-4 (exact in f16)
}

// per-pixel core: grad + folded weight -> packed 8-bin f16 contrib (16B)
// (octant-direct binning + 64-bit-shift pack: validated; R7 scalar form)
__device__ __forceinline__ uint4 pixel_contrib(float gx, float gy, float w) {
    float X = gx + 1e-10f;
    float mag = __builtin_amdgcn_sqrtf(fmaf(gx, gx, fmaf(gy, gy, 1e-10f))) * w;

    float ax = fabsf(X), ay = fabsf(gy);
    float mx = fmaxf(ax, ay), mn = fminf(ax, ay);
    float r = mn * __builtin_amdgcn_rcpf(fmaxf(mx, 1e-30f));
    float r2 = r * r;
    float a4 = fmaf(r2, -0.0149238f, 0.0670406f);
    a4 = fmaf(r2, a4, -0.1482457f);
    a4 = fmaf(r2, a4, 0.2464287f);
    a4 = fmaf(r2, a4, -0.4235106f);
    a4 = fmaf(r2, a4, 1.2732106f);
    a4 *= r;

    bool sw = ay > ax;
    bool xn = X < 0.0f;
    bool yn = gy < 0.0f;
    int q = (xn ? 2 : 0) + ((sw != xn) ? 1 : 0);
    int b0 = yn ? 7 - q : q;              // bin for (1-w1) mass
    bool f = (sw != xn) != yn;
    float ma = a4 * mag;
    float mb = mag - ma;
    float v0 = f ? ma : mb;               // mass for bin b0
    float v1 = f ? mb : ma;               // mass for bin (b0+1)&7

    unsigned combo = __builtin_bit_cast(unsigned, __builtin_amdgcn_cvt_pkrtz(v0, v1));
    int sh = (b0 & 3) << 4;
    unsigned long long A = (unsigned long long)combo << sh;
    unsigned long long B = ((b0 & 3) == 3) ? (unsigned long long)(combo >> 16) : 0ull;
    bool lohalf = b0 < 4;
    unsigned long long lo = lohalf ? A : B;
    unsigned long long hi = lohalf ? B : A;
    uint4 cw;
    cw.x = (unsigned)lo; cw.y = (unsigned)(lo >> 32);
    cw.z = (unsigned)hi; cw.w = (unsigned)(hi >> 32);
    return cw;
}

__device__ __forceinline__ __half2 u2h2(unsigned v) {
    return __builtin_bit_cast(__half2, v);
}

// lane i <- lane i-1 within its 16-lane DPP row; row-start lanes -> 0
__device__ __forceinline__ unsigned dpp_prev(unsigned v) {
    return (unsigned)__builtin_amdgcn_update_dpp(0, (int)v, 0x111, 0xF, 0xF, true); // row_shr:1
}
// lane i <- lane i+1 within its 16-lane DPP row; row-end lanes -> 0
__device__ __forceinline__ unsigned dpp_next(unsigned v) {
    return (unsigned)__builtin_amdgcn_update_dpp(0, (int)v, 0x101, 0xF, 0xF, true); // row_shl:1
}

// R14: WAVE-AUTONOMOUS design — one wave = one patch, ZERO barriers.
// Evidence R7-R13: wall pinned ~42us across prefetch/dbuf/merge/fence
// variants; W cut 16% twice with flat wall; VALUBusy 52-57%. The invariant
// was the barrier-locked 3-wave rhythm (1-wave P4' tail + barrier skew,
// phase-correlated across all blocks). Here each wave loops 3x over the
// 164 (row,ox) units (u = 64*it + lane): quad alignment (lane%4 == ox) and
// 16-lane DPP-row boundaries land exactly on the already-masked ox0/ox3
// edges, so the validated DPP exchange logic carries over verbatim.
// All inter-phase ordering is intra-wave (compiler lgkm/vmcnt waits).
// LDS: 3x(patch 6724 + s_H 3920) + s_gc 192 = 32 KB -> 5 blocks/CU
// = 15 waves; barrier-free waves stall independently -> VALU saturates
// (per-SIMD demand ~3x supply) despite the lower wave count.
__global__ __launch_bounds__(NTH, 3) void sift_desc_kernel(
        const float* __restrict__ x,   // [N,1,41,41]
        const float* __restrict__ gk,  // unused: recomputed via exp2
        const float* __restrict__ pk,  // unused: recomputed exactly
        float* __restrict__ out,       // [N,128]
        int n)
{
    const int t    = threadIdx.x;
    const int lane = t & 63;
    const int wv   = t >> 6;
    const int patch = blockIdx.x * 3 + wv;

    __shared__ __align__(16) float  sW[3][PP];            // per-wave raw patch
    __shared__ __align__(16) __half sH[3][49 * HR * NB];  // per-wave hist, pads zero
    __shared__ float s_gc[48];                            // column gauss LUT (shared)

    // ---- LUT: every wave writes identical values (benign race; each wave
    // reads only after its OWN writes -> intra-wave lgkm ordering) ----
    if (lane < 48) {
        float dd = (float)(lane - 20);
        float g = __builtin_amdgcn_exp2f(dd * dd * -8.582362e-4f);
        s_gc[lane] = (lane < PATCH) ? g : 0.0f;
    }
    // ---- zero own s_H pad rows 0-3,45-48 (dwords 0..79 and 900..979) ----
    {
        unsigned* hz = (unsigned*)&sH[wv][0];
        #pragma unroll
        for (int j = 0; j < 3; ++j) {
            int idx = 64 * j + lane;
            if (idx < 160) hz[(idx < 80) ? idx : (820 + idx)] = 0u;
        }
    }
    if (patch >= n) return;     // wave-uniform exit; no barriers exist below

    // ---- stage own patch into private LDS (27 coalesced dword loads) ----
    {
        const float* gp = x + (size_t)patch * PP;
        float* wp = &sW[wv][0];
        #pragma unroll
        for (int i = 0; i < 26; ++i) wp[lane + 64 * i] = gp[lane + 64 * i];
        if (lane < PP - 26 * 64) wp[lane + 26 * 64] = gp[lane + 26 * 64];   // tail 17
    }

    const float* sC = &sW[wv][0];
    const __half2 z2 = __float2half2_rn(0.0f);

    // ---- P1+P2: 3 iterations over units u = 64*it + lane (u < 164) ----
    #pragma unroll
    for (int it = 0; it < 3; ++it) {
        const int u = 64 * it + lane;
        if (u < PATCH * 4) {
            const int row = u >> 2;
            const int ox  = u & 3;
            const int cb  = ox * STRIDE;
            const bool ox0 = (ox == 0);
            const bool ox3 = (ox == 3);
            const int rb = row * PATCH + cb;
            const int ru = (row > 0 ? row - 1 : 0) * PATCH + cb;
            const int rd = (row < PATCH - 1 ? row + 1 : PATCH - 1) * PATCH + cb;

            const float drow = (float)(row - 20);
            const float rf = __builtin_amdgcn_exp2f(drow * drow * -8.582362e-4f);

            const __half2 wl[4] = {
                ox0 ? z2 : __float2half2_rn(tri16(0)),
                ox0 ? z2 : __float2half2_rn(tri16(1)),
                ox0 ? z2 : __float2half2_rn(tri16(2)),
                ox0 ? z2 : __float2half2_rn(tri16(3))
            };

            float m[13], uu[11], dd[11], w[11];
            m[0]  = sC[rb + (ox0 ? 0 : -1)];     // clamp == replicate pad
            #pragma unroll
            for (int i = 1; i < 12; ++i) m[i] = sC[rb + i - 1];
            m[12] = sC[rb + (ox3 ? 10 : 11)];
            #pragma unroll
            for (int i = 0; i < 11; ++i) uu[i] = sC[ru + i];
            #pragma unroll
            for (int i = 0; i < 11; ++i) dd[i] = sC[rd + i];
            #pragma unroll
            for (int i = 0; i < 11; ++i) w[i] = s_gc[cb + i] * rf;   // validated numerics

            __half2 a0 = z2, a1 = z2, a2 = z2, a3 = z2;

            #pragma unroll
            for (int k = 0; k <= 10; ++k) {
                uint4 cw = pixel_contrib(m[k + 2] - m[k], dd[k] - uu[k], w[k]);

                const __half2 wo = __float2half2_rn(tri16(k + 4));
                a0 = __hfma2(u2h2(cw.x), wo, a0);
                a1 = __hfma2(u2h2(cw.y), wo, a1);
                a2 = __hfma2(u2h2(cw.z), wo, a2);
                a3 = __hfma2(u2h2(cw.w), wo, a3);

                if (k == 1) {
                    // kx=15 = right lane's k=1; ox3 masked (OOB + possibly
                    // stale/inactive DPP source at iteration edges)
                    unsigned rx = dpp_next(cw.x);
                    unsigned ry = dpp_next(cw.y);
                    unsigned rz = dpp_next(cw.z);
                    unsigned rw = dpp_next(cw.w);
                    rx = ox3 ? 0u : rx;  ry = ox3 ? 0u : ry;
                    rz = ox3 ? 0u : rz;  rw = ox3 ? 0u : rw;
                    const __half2 wr = __float2half2_rn(tri16(15));
                    a0 = __hfma2(u2h2(rx), wr, a0);
                    a1 = __hfma2(u2h2(ry), wr, a1);
                    a2 = __hfma2(u2h2(rz), wr, a2);
                    a3 = __hfma2(u2h2(rw), wr, a3);
                }
                if (k >= 6 && k < 10) {
                    // kx=k-6 = left lane's k=6..9 ONLY (k=10 dup was R1 bug);
                    // ox0 zero-weight kills cross-row/stale data; lane-0 /
                    // 16-row starts DPP-zero. All boundary cases == masked.
                    const __half2 wk = wl[k - 6];
                    a0 = __hfma2(u2h2(dpp_prev(cw.x)), wk, a0);
                    a1 = __hfma2(u2h2(dpp_prev(cw.y)), wk, a1);
                    a2 = __hfma2(u2h2(dpp_prev(cw.z)), wk, a2);
                    a3 = __hfma2(u2h2(dpp_prev(cw.w)), wk, a3);
                }
            }

            uint4 hv;
            hv.x = __builtin_bit_cast(unsigned, a0);
            hv.y = __builtin_bit_cast(unsigned, a1);
            hv.z = __builtin_bit_cast(unsigned, a2);
            hv.w = __builtin_bit_cast(unsigned, a3);
            *(uint4*)&sH[wv][((row + 4) * HR + ox) * NB] = hv;   // phys row = row+4
        }
    }

    // ---- P4': pool+normalize, whole wave (64 lanes). Same fmaf ky order
    // as validated -> bit-identical. Intra-wave lgkm ordering vs P1 writes.
    {
        const int b   = lane >> 4;
        const int oy  = (lane >> 2) & 3;
        const int oxx = lane & 3;
        const __half* hp = &sH[wv][(oy * STRIDE * HR + oxx) * NB + b];
        float a = 0.0f, bb = 0.0f;
        #pragma unroll
        for (int ky = 0; ky < 16; ++ky) {
            a  = fmaf(tri16(ky), __half2float(hp[ky * HR * NB]),     a);
            bb = fmaf(tri16(ky), __half2float(hp[ky * HR * NB + 4]), bb);
        }

        float ss = fmaf(a, a, bb * bb);
        #pragma unroll
        for (int o = 32; o > 0; o >>= 1) ss += __shfl_xor(ss, o);
        float inv = 1.0f / fmaxf(__builtin_amdgcn_sqrtf(ss), 1e-12f);
        a  = fminf(fmaxf(a * inv, 0.0f), 0.2f);
        bb = fminf(fmaxf(bb * inv, 0.0f), 0.2f);

        float ss2 = fmaf(a, a, bb * bb);
        #pragma unroll
        for (int o = 32; o > 0; o >>= 1) ss2 += __shfl_xor(ss2, o);
        float inv2 = 1.0f / fmaxf(__builtin_amdgcn_sqrtf(ss2), 1e-12f);
        a *= inv2; bb *= inv2;

        float l1 = a + bb;                     // both >= 0 after clip
        #pragma unroll
        for (int o = 32; o > 0; o >>= 1) l1 += __shfl_xor(l1, o);
        float invl = 1.0f / fmaxf(l1, 1e-12f);

        float* op = out + (size_t)patch * 128;
        op[lane]      = __builtin_amdgcn_sqrtf(fmaf(a,  invl, 1e-10f));
        op[lane + 64] = __builtin_amdgcn_sqrtf(fmaf(bb, invl, 1e-10f));
    }
}

extern "C" void kernel_launch(void* const* d_in, const int* in_sizes, int n_in,
                              void* d_out, int out_size, void* d_ws, size_t ws_size,
                              hipStream_t stream) {
    const float* x  = (const float*)d_in[0];
    const float* gk = (const float*)d_in[1];
    const float* pk = (const float*)d_in[2];
    float* out = (float*)d_out;
    const int n = in_sizes[0] / PP;   // 8192 patches
    const int grid = (n + 2) / 3;     // one patch per wave, 3 waves per block
    sift_desc_kernel<<<grid, NTH, 0, stream>>>(x, gk, pk, out, n);
}